// Round 8
// baseline (306.466 us; speedup 1.0000x reference)
//
#include <hip/hip_runtime.h>
#include <hip/hip_bf16.h>

// Problem constants
#define BATCH 2
#define CIN   1024
#define NN    2048
#define HEADS 16
#define DHEAD 64
#define HDIM  1024
#define O3    3072
#define QSCALE 0.125f
// 0.125 * log2(e): Q pre-scale so softmax runs in exp2 domain
#define QSCALE_L2E 0.18033688011112042f
#define QSZ ((size_t)BATCH * HEADS * NN * DHEAD)  // 4,194,304 elements

typedef unsigned short ushort_t;
typedef __attribute__((ext_vector_type(8))) short bf16x8;
typedef __attribute__((ext_vector_type(8))) unsigned short ushort8;
typedef __attribute__((ext_vector_type(4))) unsigned short ushort4v;
typedef __attribute__((ext_vector_type(16))) float f32x16;

__device__ inline ushort_t f2bf(float f) {
    unsigned u = __builtin_bit_cast(unsigned, f);
    unsigned r = u + 0x7fffu + ((u >> 16) & 1u);
    return (ushort_t)(r >> 16);
}
__device__ inline float bf2f(ushort_t h) {
    return __builtin_bit_cast(float, (unsigned)h << 16);
}
__device__ inline f32x16 mfma32(bf16x8 a, bf16x8 b, f32x16 c) {
    return __builtin_amdgcn_mfma_f32_32x32x16_bf16(a, b, c, 0, 0, 0);
}
// packed 2xbf16 (RNE): low half = bf16(a), high half = bf16(b)
__device__ inline unsigned cvt_pk_bf16(float a, float b) {
    unsigned r;
    asm("v_cvt_pk_bf16_f32 %0, %1, %2" : "=v"(r) : "v"(a), "v"(b));
    return r;
}
__device__ inline float lo_f(unsigned p) {
    return __builtin_bit_cast(float, p << 16);
}
__device__ inline float hi_f(unsigned p) {
    return __builtin_bit_cast(float, p & 0xffff0000u);
}

union U4 { unsigned u[4]; bf16x8 v; };

// global -> LDS direct (16B per lane); LDS dest is wave-uniform base + lane*16
#define GLDS(gp, lp) __builtin_amdgcn_global_load_lds( \
    (__attribute__((address_space(1))) void*)(gp),     \
    (__attribute__((address_space(3))) void*)(lp), 16, 0, 0)

// ---------------- elementwise f32 -> bf16 hi/lo split ----------------
__global__ __launch_bounds__(256) void convert_split(const float* __restrict__ in,
                                                     ushort_t* __restrict__ hi,
                                                     ushort_t* __restrict__ lo,
                                                     int n8) {
    int t = blockIdx.x * 256 + threadIdx.x;
    if (t >= n8) return;
    size_t base = (size_t)t * 8;
    float4 a = *(const float4*)(in + base);
    float4 b = *(const float4*)(in + base + 4);
    float v[8] = {a.x, a.y, a.z, a.w, b.x, b.y, b.z, b.w};
    ushort8 hv, lv;
#pragma unroll
    for (int i = 0; i < 8; ++i) {
        ushort_t h = f2bf(v[i]);
        hv[i] = h;
        lv[i] = f2bf(v[i] - bf2f(h));
    }
    *(ushort8*)(hi + base) = hv;
    *(ushort8*)(lo + base) = lv;
}

// ------------- transpose + split: in f32 [B][CIN][NN] -> out hi/lo [B][NN][CIN] -------------
__global__ __launch_bounds__(256) void transpose_cvt(const float* __restrict__ in,
                                                     ushort_t* __restrict__ th,
                                                     ushort_t* __restrict__ tl) {
    __shared__ float T[32][33];
    const int b = blockIdx.z;
    const int n0 = blockIdx.x * 32, c0 = blockIdx.y * 32;
    const int t = threadIdx.x;
    const int r = t >> 3, q = t & 7;
    float4 v = *(const float4*)(in + ((size_t)b * CIN + c0 + r) * NN + n0 + q * 4);
    T[r][q * 4 + 0] = v.x; T[r][q * 4 + 1] = v.y;
    T[r][q * 4 + 2] = v.z; T[r][q * 4 + 3] = v.w;
    __syncthreads();
    ushort4v hv, lv;
#pragma unroll
    for (int i = 0; i < 4; ++i) {
        float f = T[q * 4 + i][r];
        ushort_t h = f2bf(f);
        hv[i] = h;
        lv[i] = f2bf(f - bf2f(h));
    }
    size_t o = ((size_t)b * NN + n0 + r) * CIN + c0 + q * 4;
    *(ushort4v*)(th + o) = hv;
    *(ushort4v*)(tl + o) = lv;
}

// ---------------- MFMA split-bf16 GEMM ----------------
// MODE 0: QKV epilogue. Q: [bh][n][64] plain, scaled by 0.125*log2e.
// K: granule^(row&7) swizzled. V: [b*1024+ch][n], n-granule^(ch&7) swizzled.
// MODE 1: f32 out + bias
template<int MODE>
__global__ __launch_bounds__(256, 3) void gemm_mfma(
    const ushort_t* __restrict__ Ah, const ushort_t* __restrict__ Al,
    const ushort_t* __restrict__ Bth, const ushort_t* __restrict__ Btl,
    const float* __restrict__ bias, float* __restrict__ outF,
    ushort_t* __restrict__ Qh, ushort_t* __restrict__ Ql,
    ushort_t* __restrict__ Kh, ushort_t* __restrict__ Kl,
    ushort_t* __restrict__ Vh, ushort_t* __restrict__ Vl) {

    __shared__ __align__(16) ushort_t lsAh[4096], lsAl[4096], lsBh[4096], lsBl[4096];

    const int b  = blockIdx.z;
    const int n0 = blockIdx.x * 128;
    const int m0 = blockIdx.y * 128;
    const int tid = threadIdx.x;
    const int wave = tid >> 6, lane = tid & 63;
    const int l31 = lane & 31, hi5 = lane >> 5;
    const int wr = wave >> 1, wc = wave & 1;

    const int srow = lane >> 2;
    const int kswz = 8 * ((lane & 3) ^ ((lane >> 3) & 3));
    const ushort_t* gAh = Ah  + (size_t)(m0 + wave * 16 + srow) * CIN + kswz;
    const ushort_t* gAl = Al  + (size_t)(m0 + wave * 16 + srow) * CIN + kswz;
    const ushort_t* gBh = Bth + ((size_t)b * NN + n0 + wave * 16 + srow) * CIN + kswz;
    const ushort_t* gBl = Btl + ((size_t)b * NN + n0 + wave * 16 + srow) * CIN + kswz;
    ushort_t* dAh = lsAh + wave * 512;
    ushort_t* dAl = lsAl + wave * 512;
    ushort_t* dBh = lsBh + wave * 512;
    ushort_t* dBl = lsBl + wave * 512;

    const int rswz = ((l31 >> 1) & 3) * 8;
    int offA[2][2], offB[2][2];
#pragma unroll
    for (int f = 0; f < 2; ++f)
#pragma unroll
        for (int kh = 0; kh < 2; ++kh) {
            offA[f][kh] = (wr * 64 + f * 32 + l31) * 64 + ((kh * 16 + hi5 * 8) ^ rswz) * 2;
            offB[f][kh] = (wc * 64 + f * 32 + l31) * 64 + ((kh * 16 + hi5 * 8) ^ rswz) * 2;
        }

    f32x16 acc[2][2];
#pragma unroll
    for (int i = 0; i < 2; ++i)
#pragma unroll
        for (int j = 0; j < 2; ++j)
#pragma unroll
            for (int r = 0; r < 16; ++r) acc[i][j][r] = 0.f;

    for (int k0 = 0; k0 < CIN; k0 += 32) {
        __syncthreads();
        GLDS(gAh + k0,            dAh);
        GLDS(gAh + 64 * CIN + k0, dAh + 2048);
        GLDS(gAl + k0,            dAl);
        GLDS(gAl + 64 * CIN + k0, dAl + 2048);
        GLDS(gBh + k0,            dBh);
        GLDS(gBh + 64 * CIN + k0, dBh + 2048);
        GLDS(gBl + k0,            dBl);
        GLDS(gBl + 64 * CIN + k0, dBl + 2048);
        __syncthreads();
#pragma unroll
        for (int kh = 0; kh < 2; ++kh) {
            bf16x8 a_h[2], a_l[2], b_h[2], b_l[2];
#pragma unroll
            for (int f = 0; f < 2; ++f) {
                a_h[f] = *(const bf16x8*)((const char*)lsAh + offA[f][kh]);
                a_l[f] = *(const bf16x8*)((const char*)lsAl + offA[f][kh]);
                b_h[f] = *(const bf16x8*)((const char*)lsBh + offB[f][kh]);
                b_l[f] = *(const bf16x8*)((const char*)lsBl + offB[f][kh]);
            }
#pragma unroll
            for (int fi = 0; fi < 2; ++fi)
#pragma unroll
                for (int fj = 0; fj < 2; ++fj) {
                    acc[fi][fj] = mfma32(a_l[fi], b_h[fj], acc[fi][fj]);
                    acc[fi][fj] = mfma32(a_h[fi], b_l[fj], acc[fi][fj]);
                    acc[fi][fj] = mfma32(a_h[fi], b_h[fj], acc[fi][fj]);
                }
        }
    }

    const int nn = n0 + wc * 64 + l31;

    if constexpr (MODE == 0) {
        const int region = m0 >> 10;  // 0=Q 1=K 2=V (uniform per block)
        if (region < 2) {
            const float scale = (region == 0) ? QSCALE_L2E : 1.0f;
            ushort_t* H = (region == 0) ? Qh : Kh;
            ushort_t* L = (region == 0) ? Ql : Kl;
            const int head = ((m0 & 1023) >> 6) + wr;
            const size_t bh_base = (size_t)(b * HEADS + head) * NN;
#pragma unroll
            for (int fj = 0; fj < 2; ++fj) {
                const size_t rowb = (bh_base + nn + fj * 32) * DHEAD;
#pragma unroll
                for (int fi = 0; fi < 2; ++fi) {
#pragma unroll
                    for (int g = 0; g < 4; ++g) {
                        ushort4v hv, lv;
#pragma unroll
                        for (int i = 0; i < 4; ++i) {
                            float f = acc[fi][fj][4 * g + i] * scale;
                            ushort_t h2 = f2bf(f);
                            hv[i] = h2;
                            lv[i] = f2bf(f - bf2f(h2));
                        }
                        // K gets granule swizzle ^(row&7); row&7 == l31&7
                        const int e = (region == 1)
                            ? (((fi * 4 + g) ^ (l31 & 7)) * 8 + 4 * hi5)
                            : (fi * 32 + 4 * hi5 + 8 * g);
                        *(ushort4v*)(H + rowb + e) = hv;
                        *(ushort4v*)(L + rowb + e) = lv;
                    }
                }
            }
        } else {
            const int ch0 = (m0 - 2048) + wr * 64;
#pragma unroll
            for (int fi = 0; fi < 2; ++fi)
#pragma unroll
                for (int fj = 0; fj < 2; ++fj)
#pragma unroll
                    for (int r = 0; r < 16; ++r) {
                        const int ch = ch0 + fi * 32 + (r & 3) + 8 * (r >> 2) + 4 * hi5;
                        const int g6 = (fj * 4 + (l31 >> 3)) ^ ((r & 3) + 4 * hi5);
                        const int n_ = n0 + wc * 64 + g6 * 8 + (l31 & 7);
                        const size_t idx = ((size_t)b * HDIM + ch) * NN + n_;
                        float f = acc[fi][fj][r];
                        ushort_t h2 = f2bf(f);
                        Vh[idx] = h2;
                        Vl[idx] = f2bf(f - bf2f(h2));
                    }
        }
    } else {
#pragma unroll
        for (int fi = 0; fi < 2; ++fi)
#pragma unroll
            for (int fj = 0; fj < 2; ++fj)
#pragma unroll
                for (int r = 0; r < 16; ++r) {
                    const int mrow = m0 + wr * 64 + fi * 32 + (r & 3) + 8 * (r >> 2) + 4 * hi5;
                    outF[((size_t)b * CIN + mrow) * NN + nn + fj * 32] =
                        acc[fi][fj][r] + bias[mrow];
                }
    }
}

// ---------------- attention v7: 64q/wave, split-KV 2-way, m=0 softmax ----------------
// 512 blocks: [kv-major-last] 256 kv=0 blocks then 256 kv=1. Each block: 4 waves
// x 64 queries, scans its 1024-key half with LDS-staged dbuf 64-key tiles.
// Fixed softmax base m=0 (safe: |s_bits| <~ 10) -> linear combine.
// kv=0 writes raw O partial (P1, f32) + l; kv=1 spins on flag, adds, normalizes,
// writes aot hi/lo via LDS transpose.
__global__ __launch_bounds__(256, 2) void attn_mfma(
    const ushort_t* __restrict__ Qh, const ushort_t* __restrict__ Ql,
    const ushort_t* __restrict__ Kh, const ushort_t* __restrict__ Kl,
    const ushort_t* __restrict__ Vh, const ushort_t* __restrict__ Vl,
    ushort_t* __restrict__ aoth, ushort_t* __restrict__ aotl,
    float* __restrict__ P1, float* __restrict__ l1buf, int* __restrict__ flags) {

    __shared__ __align__(16) ushort_t smem[32768];  // 64KB: staging, then oS

    const int bid = blockIdx.x;
    const int kv = bid >> 8;
    const int r_ = bid & 255;
    const int slot = r_ & 7;
    const int rest = r_ >> 3;              // 0..31
    const int bh = slot * 4 + (rest >> 3); // 4 bh per xcd-slot
    const int qt = rest & 7;
    const int b = bh >> 4, h = bh & 15;

    const int wave = threadIdx.x >> 6;
    const int lane = threadIdx.x & 63;
    const int l31 = lane & 31;
    const int hi5 = lane >> 5;
    const int r7 = l31 & 7;
    const int q0 = qt * 256 + wave * 64;
    const int kvbase = kv * 1024;
    const int fidx = bh * 8 + qt;

    // Q fragments, 2 qgroups of 32
    bf16x8 qfh[2][4], qfl[2][4];
#pragma unroll
    for (int g = 0; g < 2; ++g) {
        const ushort_t* qb  = Qh + ((size_t)bh * NN + q0 + g * 32 + l31) * DHEAD + hi5 * 8;
        const ushort_t* qlb = Ql + ((size_t)bh * NN + q0 + g * 32 + l31) * DHEAD + hi5 * 8;
#pragma unroll
        for (int c = 0; c < 4; ++c) {
            qfh[g][c] = *(const bf16x8*)(qb + c * 16);
            qfl[g][c] = *(const bf16x8*)(qlb + c * 16);
        }
    }

    // staging: wave 0->Kh 1->Kl 2->Vh 3->Vl
    const size_t kbase = (size_t)bh * NN * DHEAD;
    const size_t vbase = (size_t)bh * DHEAD * NN;
    const ushort_t* gsel = (wave == 0) ? Kh + kbase
                         : (wave == 1) ? Kl + kbase
                         : (wave == 2) ? Vh + vbase
                                       : Vl + vbase;
    ushort_t* lsel = smem + ((wave == 0) ? 0 : (wave == 1) ? 8192
                           : (wave == 2) ? 16384 : 24576);
    const bool isK = wave < 2;
    const int sr = lane >> 3, sg = lane & 7;

#define STAGE(BUF, J0)                                                         \
    {                                                                          \
        ushort_t* dst_ = lsel + (BUF) * 4096;                                  \
        _Pragma("unroll") for (int i_ = 0; i_ < 8; ++i_) {                     \
            const ushort_t* s_ = isK                                           \
                ? gsel + (size_t)((J0) + i_ * 8 + sr) * DHEAD + sg * 8         \
                : gsel + (size_t)(i_ * 8 + sr) * NN + (J0) + sg * 8;           \
            GLDS(s_, dst_ + i_ * 512);                                         \
        }                                                                      \
    }

    f32x16 o[2][2], zz;
#pragma unroll
    for (int r = 0; r < 16; ++r) zz[r] = 0.f;
#pragma unroll
    for (int g = 0; g < 2; ++g)
#pragma unroll
        for (int dt = 0; dt < 2; ++dt)
#pragma unroll
            for (int r = 0; r < 16; ++r) o[g][dt][r] = 0.f;
    float lacc[2] = {0.f, 0.f};

    STAGE(0, kvbase);
    __syncthreads();

#pragma unroll 1
    for (int t = 0; t < 16; ++t) {
        const int buf = t & 1;
        if (t < 15) STAGE(buf ^ 1, kvbase + (t + 1) * 64);

#pragma unroll
        for (int js = 0; js < 2; ++js) {
            // K fragments (shared by both qgroups)
            bf16x8 kh_[4], kl_[4];
            const int kro = (js * 32 + l31) * 64;
#pragma unroll
            for (int c = 0; c < 4; ++c) {
                const int go = ((2 * c + hi5) ^ r7) * 8;
                kh_[c] = *(const bf16x8*)(smem + buf * 4096 + kro + go);
                kl_[c] = *(const bf16x8*)(smem + 8192 + buf * 4096 + kro + go);
            }
            // QK^T + exp2 per qgroup (m = 0 fixed)
            f32x16 sv[2];
#pragma unroll
            for (int g = 0; g < 2; ++g) {
                __builtin_amdgcn_s_setprio(1);
                f32x16 sA = mfma32(kh_[0], qfh[g][0], zz);
                sA = mfma32(kl_[0], qfh[g][0], sA);
                sA = mfma32(kh_[0], qfl[g][0], sA);
                sA = mfma32(kh_[1], qfh[g][1], sA);
                sA = mfma32(kl_[1], qfh[g][1], sA);
                sA = mfma32(kh_[1], qfl[g][1], sA);
                f32x16 sB = mfma32(kh_[2], qfh[g][2], zz);
                sB = mfma32(kl_[2], qfh[g][2], sB);
                sB = mfma32(kh_[2], qfl[g][2], sB);
                sB = mfma32(kh_[3], qfh[g][3], sB);
                sB = mfma32(kl_[3], qfh[g][3], sB);
                sB = mfma32(kh_[3], qfl[g][3], sB);
                __builtin_amdgcn_s_setprio(0);
                float ps = 0.f;
#pragma unroll
                for (int r = 0; r < 16; ++r) {
                    float e = __builtin_amdgcn_exp2f(sA[r] + sB[r]);
                    sv[g][r] = e;
                    ps += e;
                }
                lacc[g] += ps + __shfl_xor(ps, 32);
            }

            // pack P (hi/lo) per qgroup, blend-shuffle, PV sharing V loads
#pragma unroll
            for (int jc = 0; jc < 2; ++jc) {
                bf16x8 pBh[2], pBl[2];
#pragma unroll
                for (int g = 0; g < 2; ++g) {
                    unsigned P0 = cvt_pk_bf16(sv[g][8 * jc + 0], sv[g][8 * jc + 1]);
                    unsigned P1w = cvt_pk_bf16(sv[g][8 * jc + 2], sv[g][8 * jc + 3]);
                    unsigned P2 = cvt_pk_bf16(sv[g][8 * jc + 4], sv[g][8 * jc + 5]);
                    unsigned P3 = cvt_pk_bf16(sv[g][8 * jc + 6], sv[g][8 * jc + 7]);
                    unsigned L0 = cvt_pk_bf16(sv[g][8 * jc + 0] - lo_f(P0),
                                              sv[g][8 * jc + 1] - hi_f(P0));
                    unsigned L1 = cvt_pk_bf16(sv[g][8 * jc + 2] - lo_f(P1w),
                                              sv[g][8 * jc + 3] - hi_f(P1w));
                    unsigned L2 = cvt_pk_bf16(sv[g][8 * jc + 4] - lo_f(P2),
                                              sv[g][8 * jc + 5] - hi_f(P2));
                    unsigned L3 = cvt_pk_bf16(sv[g][8 * jc + 6] - lo_f(P3),
                                              sv[g][8 * jc + 7] - hi_f(P3));
                    unsigned ta = hi5 ? P0 : P2, tb = hi5 ? P1w : P3;
                    unsigned ua = hi5 ? L0 : L2, ub = hi5 ? L1 : L3;
                    unsigned sa = __shfl_xor((int)ta, 32), sb = __shfl_xor((int)tb, 32);
                    unsigned va = __shfl_xor((int)ua, 32), vb = __shfl_xor((int)ub, 32);
                    U4 th, tl;
                    th.u[0] = hi5 ? sa : P0;  th.u[1] = hi5 ? sb : P1w;
                    th.u[2] = hi5 ? P2 : sa;  th.u[3] = hi5 ? P3 : sb;
                    tl.u[0] = hi5 ? va : L0;  tl.u[1] = hi5 ? vb : L1;
                    tl.u[2] = hi5 ? L2 : va;  tl.u[3] = hi5 ? L3 : vb;
                    pBh[g] = th.v;
                    pBl[g] = tl.v;
                }
#pragma unroll
                for (int dt = 0; dt < 2; ++dt) {
                    const int vro = (dt * 32 + l31) * 64;
                    const int vgo = ((js * 4 + jc * 2 + hi5) ^ r7) * 8;
                    bf16x8 vh_ = *(const bf16x8*)(smem + 16384 + buf * 4096 + vro + vgo);
                    bf16x8 vl_ = *(const bf16x8*)(smem + 24576 + buf * 4096 + vro + vgo);
                    __builtin_amdgcn_s_setprio(1);
                    o[0][dt] = mfma32(vh_, pBh[0], o[0][dt]);
                    o[0][dt] = mfma32(vh_, pBl[0], o[0][dt]);
                    o[0][dt] = mfma32(vl_, pBh[0], o[0][dt]);
                    o[1][dt] = mfma32(vh_, pBh[1], o[1][dt]);
                    o[1][dt] = mfma32(vh_, pBl[1], o[1][dt]);
                    o[1][dt] = mfma32(vl_, pBh[1], o[1][dt]);
                    __builtin_amdgcn_s_setprio(0);
                }
            }
        }
        __syncthreads();
    }
#undef STAGE

    if (kv == 0) {
        // write raw partials
        float* basep = P1 + (size_t)fidx * 16384;
#pragma unroll
        for (int g = 0; g < 2; ++g)
#pragma unroll
            for (int dt = 0; dt < 2; ++dt)
#pragma unroll
                for (int r = 0; r < 16; ++r)
                    basep[(((wave * 2 + g) * 2 + dt) * 16 + r) * 64 + lane] = o[g][dt][r];
        if (hi5 == 0) {
#pragma unroll
            for (int g = 0; g < 2; ++g)
                l1buf[fidx * 256 + wave * 64 + g * 32 + l31] = lacc[g];
        }
        __threadfence();
        __syncthreads();
        if (threadIdx.x == 0)
            __hip_atomic_store(flags + fidx, 1, __ATOMIC_RELEASE, __HIP_MEMORY_SCOPE_AGENT);
    } else {
        if (threadIdx.x == 0) {
            while (__hip_atomic_load(flags + fidx, __ATOMIC_ACQUIRE,
                                     __HIP_MEMORY_SCOPE_AGENT) == 0)
                __builtin_amdgcn_s_sleep(8);
        }
        __syncthreads();
        __threadfence();
        const float* basep = P1 + (size_t)fidx * 16384;
        float inv[2];
#pragma unroll
        for (int g = 0; g < 2; ++g) {
            float l1r = l1buf[fidx * 256 + wave * 64 + g * 32 + l31];
            inv[g] = 1.0f / (lacc[g] + l1r);
        }
        ushort_t* oSh = smem;             // 32KB
        ushort_t* oSl = smem + 16384;     // 32KB
#pragma unroll
        for (int g = 0; g < 2; ++g)
#pragma unroll
            for (int dt = 0; dt < 2; ++dt)
#pragma unroll
                for (int r = 0; r < 16; ++r) {
                    float val = (o[g][dt][r] +
                                 basep[(((wave * 2 + g) * 2 + dt) * 16 + r) * 64 + lane]) *
                                inv[g];
                    const int ql_ = wave * 64 + g * 32 + l31;
                    const int d = dt * 32 + (r & 3) + 8 * (r >> 2) + 4 * hi5;
                    const int dsw = d ^ ((ql_ & 7) << 3);
                    ushort_t hh = f2bf(val);
                    oSh[ql_ * 64 + dsw] = hh;
                    oSl[ql_ * 64 + dsw] = f2bf(val - bf2f(hh));
                }
        __syncthreads();
        // coalesced row writes: thread t -> query row t
        const int t = threadIdx.x;
        const size_t rowaddr = ((size_t)b * NN + qt * 256 + t) * HDIM + h * 64;
#pragma unroll
        for (int gg = 0; gg < 8; ++gg) {
            const int ggr = (gg + (t & 7)) & 7;      // staggered, conflict-free
            ushort8 hv = *(const ushort8*)(oSh + t * 64 + ggr * 8);
            ushort8 lv = *(const ushort8*)(oSl + t * 64 + ggr * 8);
            const int dbase = (ggr ^ (t & 7)) * 8;   // unswizzle
            *(ushort8*)(aoth + rowaddr + dbase) = hv;
            *(ushort8*)(aotl + rowaddr + dbase) = lv;
        }
    }
}

// ---------------- launch ----------------
extern "C" void kernel_launch(void* const* d_in, const int* in_sizes, int n_in,
                              void* d_out, int out_size, void* d_ws, size_t ws_size,
                              hipStream_t stream) {
    const float* x     = (const float*)d_in[0];
    const float* w_qkv = (const float*)d_in[1];
    const float* w_out = (const float*)d_in[2];
    const float* b_out = (const float*)d_in[3];
    float* out = (float*)d_out;

    ushort_t* ws_u = (ushort_t*)d_ws;
    ushort_t* Qh = ws_u;
    ushort_t* Ql = Qh + QSZ;
    ushort_t* Kh = Ql + QSZ;
    ushort_t* Kl = Kh + QSZ;
    ushort_t* Vh = Kl + QSZ;
    ushort_t* Vl = Vh + QSZ;
    ushort_t* shared_u = ws_u + 6 * QSZ;          // 16.78 MB region
    ushort_t* wqh = shared_u;
    ushort_t* wql = wqh + (size_t)O3 * CIN;
    ushort_t* aoth = shared_u;                    // aot hi/lo (written by attn kv=1)
    ushort_t* aotl = aoth + (size_t)BATCH * NN * HDIM;
    ushort_t* woh = ws_u;                         // w_out hi/lo into dead Q region
    ushort_t* wol = woh + (size_t)CIN * HDIM;
    ushort_t* xth = (ushort_t*)d_out;             // xt scratch in d_out (dead later)
    ushort_t* xtl = xth + (size_t)BATCH * NN * CIN;

    // partials: P1 (kv=0 raw O sums, f32) fills d_out exactly; l1 + flags at ws tail
    const size_t base_bytes = (6 * QSZ + 2 * (size_t)BATCH * NN * CIN) * sizeof(ushort_t);
    float* P1 = (float*)d_out;
    float* l1buf = (float*)((char*)d_ws + base_bytes);
    int* flags = (int*)((char*)d_ws + base_bytes + 262144);
    if (ws_size < base_bytes + 262144 + 1024) return;

    // 0) zero the sync flags (re-armed every launch; graph-capture safe)
    hipMemsetAsync(flags, 0, 1024, stream);

    // 1) weight + input conversions
    convert_split<<<1536, 256, 0, stream>>>(w_qkv, wqh, wql, O3 * CIN / 8);
    transpose_cvt<<<dim3(NN / 32, CIN / 32, BATCH), 256, 0, stream>>>(x, xth, xtl);

    // 2) QKV projection -> Q (exp2-scaled) plain, K/V swizzled hi/lo
    gemm_mfma<0><<<dim3(NN / 128, O3 / 128, BATCH), 256, 0, stream>>>(
        wqh, wql, xth, xtl, nullptr, nullptr, Qh, Ql, Kh, Kl, Vh, Vl);

    // 3) flash attention, split-KV with in-kernel combine -> aot hi/lo
    attn_mfma<<<dim3(512), 256, 0, stream>>>(
        Qh, Ql, Kh, Kl, Vh, Vl, aoth, aotl, P1, l1buf, flags);

    // 4) w_out conversion into dead Q region
    convert_split<<<512, 256, 0, stream>>>(w_out, woh, wol, CIN * HDIM / 8);

    // 5) output projection + bias -> out f32 (overwrites P1)
    gemm_mfma<1><<<dim3(NN / 128, HDIM / 128, BATCH), 256, 0, stream>>>(
        woh, wol, aoth, aotl, b_out, out, nullptr, nullptr, nullptr, nullptr,
        nullptr, nullptr);
}

// Round 9
// 219.748 us; speedup vs baseline: 1.3946x; 1.3946x over previous
//
#include <hip/hip_runtime.h>
#include <hip/hip_bf16.h>

// Problem constants
#define BATCH 2
#define CIN   1024
#define NN    2048
#define HEADS 16
#define DHEAD 64
#define HDIM  1024
#define O3    3072
#define QSCALE 0.125f
// 0.125 * log2(e): Q pre-scale so softmax runs in exp2 domain
#define QSCALE_L2E 0.18033688011112042f
#define QSZ ((size_t)BATCH * HEADS * NN * DHEAD)  // 4,194,304 elements

typedef unsigned short ushort_t;
typedef __attribute__((ext_vector_type(8))) short bf16x8;
typedef __attribute__((ext_vector_type(8))) unsigned short ushort8;
typedef __attribute__((ext_vector_type(4))) unsigned short ushort4v;
typedef __attribute__((ext_vector_type(16))) float f32x16;

__device__ inline ushort_t f2bf(float f) {
    unsigned u = __builtin_bit_cast(unsigned, f);
    unsigned r = u + 0x7fffu + ((u >> 16) & 1u);
    return (ushort_t)(r >> 16);
}
__device__ inline float bf2f(ushort_t h) {
    return __builtin_bit_cast(float, (unsigned)h << 16);
}
__device__ inline f32x16 mfma32(bf16x8 a, bf16x8 b, f32x16 c) {
    return __builtin_amdgcn_mfma_f32_32x32x16_bf16(a, b, c, 0, 0, 0);
}
// packed 2xbf16 (RNE): low half = bf16(a), high half = bf16(b)
__device__ inline unsigned cvt_pk_bf16(float a, float b) {
    unsigned r;
    asm("v_cvt_pk_bf16_f32 %0, %1, %2" : "=v"(r) : "v"(a), "v"(b));
    return r;
}

union U4 { unsigned u[4]; bf16x8 v; };

// global -> LDS direct (16B per lane); LDS dest is wave-uniform base + lane*16
#define GLDS(gp, lp) __builtin_amdgcn_global_load_lds( \
    (__attribute__((address_space(1))) void*)(gp),     \
    (__attribute__((address_space(3))) void*)(lp), 16, 0, 0)

// ---------------- elementwise f32 -> bf16 hi/lo split ----------------
__global__ __launch_bounds__(256) void convert_split(const float* __restrict__ in,
                                                     ushort_t* __restrict__ hi,
                                                     ushort_t* __restrict__ lo,
                                                     int n8) {
    int t = blockIdx.x * 256 + threadIdx.x;
    if (t >= n8) return;
    size_t base = (size_t)t * 8;
    float4 a = *(const float4*)(in + base);
    float4 b = *(const float4*)(in + base + 4);
    float v[8] = {a.x, a.y, a.z, a.w, b.x, b.y, b.z, b.w};
    ushort8 hv, lv;
#pragma unroll
    for (int i = 0; i < 8; ++i) {
        ushort_t h = f2bf(v[i]);
        hv[i] = h;
        lv[i] = f2bf(v[i] - bf2f(h));
    }
    *(ushort8*)(hi + base) = hv;
    *(ushort8*)(lo + base) = lv;
}

// ------------- transpose + split: in f32 [B][CIN][NN] -> out hi/lo [B][NN][CIN] -------------
__global__ __launch_bounds__(256) void transpose_cvt(const float* __restrict__ in,
                                                     ushort_t* __restrict__ th,
                                                     ushort_t* __restrict__ tl) {
    __shared__ float T[32][33];
    const int b = blockIdx.z;
    const int n0 = blockIdx.x * 32, c0 = blockIdx.y * 32;
    const int t = threadIdx.x;
    const int r = t >> 3, q = t & 7;
    float4 v = *(const float4*)(in + ((size_t)b * CIN + c0 + r) * NN + n0 + q * 4);
    T[r][q * 4 + 0] = v.x; T[r][q * 4 + 1] = v.y;
    T[r][q * 4 + 2] = v.z; T[r][q * 4 + 3] = v.w;
    __syncthreads();
    ushort4v hv, lv;
#pragma unroll
    for (int i = 0; i < 4; ++i) {
        float f = T[q * 4 + i][r];
        ushort_t h = f2bf(f);
        hv[i] = h;
        lv[i] = f2bf(f - bf2f(h));
    }
    size_t o = ((size_t)b * NN + n0 + r) * CIN + c0 + q * 4;
    *(ushort4v*)(th + o) = hv;
    *(ushort4v*)(tl + o) = lv;
}

// ---------------- MFMA split-bf16 GEMM ----------------
// MODE 0: QKV epilogue. Q: [bh][n][64] plain, scaled by 0.125*log2e.
// K: granule^(row&7) swizzled hi/lo. V: [b*1024+ch][n], n-granule^(ch&7)
// swizzled, HI ONLY (bf16 V suffices: per-key errors average in PV).
// MODE 1: f32 out + bias
template<int MODE>
__global__ __launch_bounds__(256, 3) void gemm_mfma(
    const ushort_t* __restrict__ Ah, const ushort_t* __restrict__ Al,
    const ushort_t* __restrict__ Bth, const ushort_t* __restrict__ Btl,
    const float* __restrict__ bias, float* __restrict__ outF,
    ushort_t* __restrict__ Qh, ushort_t* __restrict__ Ql,
    ushort_t* __restrict__ Kh, ushort_t* __restrict__ Kl,
    ushort_t* __restrict__ Vh) {

    __shared__ __align__(16) ushort_t lsAh[4096], lsAl[4096], lsBh[4096], lsBl[4096];

    const int b  = blockIdx.z;
    const int n0 = blockIdx.x * 128;
    const int m0 = blockIdx.y * 128;
    const int tid = threadIdx.x;
    const int wave = tid >> 6, lane = tid & 63;
    const int l31 = lane & 31, hi5 = lane >> 5;
    const int wr = wave >> 1, wc = wave & 1;

    const int srow = lane >> 2;
    const int kswz = 8 * ((lane & 3) ^ ((lane >> 3) & 3));
    const ushort_t* gAh = Ah  + (size_t)(m0 + wave * 16 + srow) * CIN + kswz;
    const ushort_t* gAl = Al  + (size_t)(m0 + wave * 16 + srow) * CIN + kswz;
    const ushort_t* gBh = Bth + ((size_t)b * NN + n0 + wave * 16 + srow) * CIN + kswz;
    const ushort_t* gBl = Btl + ((size_t)b * NN + n0 + wave * 16 + srow) * CIN + kswz;
    ushort_t* dAh = lsAh + wave * 512;
    ushort_t* dAl = lsAl + wave * 512;
    ushort_t* dBh = lsBh + wave * 512;
    ushort_t* dBl = lsBl + wave * 512;

    const int rswz = ((l31 >> 1) & 3) * 8;
    int offA[2][2], offB[2][2];
#pragma unroll
    for (int f = 0; f < 2; ++f)
#pragma unroll
        for (int kh = 0; kh < 2; ++kh) {
            offA[f][kh] = (wr * 64 + f * 32 + l31) * 64 + ((kh * 16 + hi5 * 8) ^ rswz) * 2;
            offB[f][kh] = (wc * 64 + f * 32 + l31) * 64 + ((kh * 16 + hi5 * 8) ^ rswz) * 2;
        }

    f32x16 acc[2][2];
#pragma unroll
    for (int i = 0; i < 2; ++i)
#pragma unroll
        for (int j = 0; j < 2; ++j)
#pragma unroll
            for (int r = 0; r < 16; ++r) acc[i][j][r] = 0.f;

    for (int k0 = 0; k0 < CIN; k0 += 32) {
        __syncthreads();
        GLDS(gAh + k0,            dAh);
        GLDS(gAh + 64 * CIN + k0, dAh + 2048);
        GLDS(gAl + k0,            dAl);
        GLDS(gAl + 64 * CIN + k0, dAl + 2048);
        GLDS(gBh + k0,            dBh);
        GLDS(gBh + 64 * CIN + k0, dBh + 2048);
        GLDS(gBl + k0,            dBl);
        GLDS(gBl + 64 * CIN + k0, dBl + 2048);
        __syncthreads();
#pragma unroll
        for (int kh = 0; kh < 2; ++kh) {
            bf16x8 a_h[2], a_l[2], b_h[2], b_l[2];
#pragma unroll
            for (int f = 0; f < 2; ++f) {
                a_h[f] = *(const bf16x8*)((const char*)lsAh + offA[f][kh]);
                a_l[f] = *(const bf16x8*)((const char*)lsAl + offA[f][kh]);
                b_h[f] = *(const bf16x8*)((const char*)lsBh + offB[f][kh]);
                b_l[f] = *(const bf16x8*)((const char*)lsBl + offB[f][kh]);
            }
#pragma unroll
            for (int fi = 0; fi < 2; ++fi)
#pragma unroll
                for (int fj = 0; fj < 2; ++fj) {
                    acc[fi][fj] = mfma32(a_l[fi], b_h[fj], acc[fi][fj]);
                    acc[fi][fj] = mfma32(a_h[fi], b_l[fj], acc[fi][fj]);
                    acc[fi][fj] = mfma32(a_h[fi], b_h[fj], acc[fi][fj]);
                }
        }
    }

    const int nn = n0 + wc * 64 + l31;

    if constexpr (MODE == 0) {
        const int region = m0 >> 10;  // 0=Q 1=K 2=V (uniform per block)
        if (region < 2) {
            const float scale = (region == 0) ? QSCALE_L2E : 1.0f;
            ushort_t* H = (region == 0) ? Qh : Kh;
            ushort_t* L = (region == 0) ? Ql : Kl;
            const int head = ((m0 & 1023) >> 6) + wr;
            const size_t bh_base = (size_t)(b * HEADS + head) * NN;
#pragma unroll
            for (int fj = 0; fj < 2; ++fj) {
                const size_t rowb = (bh_base + nn + fj * 32) * DHEAD;
#pragma unroll
                for (int fi = 0; fi < 2; ++fi) {
#pragma unroll
                    for (int g = 0; g < 4; ++g) {
                        ushort4v hv, lv;
#pragma unroll
                        for (int i = 0; i < 4; ++i) {
                            float f = acc[fi][fj][4 * g + i] * scale;
                            ushort_t h2 = f2bf(f);
                            hv[i] = h2;
                            lv[i] = f2bf(f - bf2f(h2));
                        }
                        // K gets granule swizzle ^(row&7); row&7 == l31&7
                        const int e = (region == 1)
                            ? (((fi * 4 + g) ^ (l31 & 7)) * 8 + 4 * hi5)
                            : (fi * 32 + 4 * hi5 + 8 * g);
                        *(ushort4v*)(H + rowb + e) = hv;
                        *(ushort4v*)(L + rowb + e) = lv;
                    }
                }
            }
        } else {
            const int ch0 = (m0 - 2048) + wr * 64;
#pragma unroll
            for (int fi = 0; fi < 2; ++fi)
#pragma unroll
                for (int fj = 0; fj < 2; ++fj)
#pragma unroll
                    for (int r = 0; r < 16; ++r) {
                        const int ch = ch0 + fi * 32 + (r & 3) + 8 * (r >> 2) + 4 * hi5;
                        const int g6 = (fj * 4 + (l31 >> 3)) ^ ((r & 3) + 4 * hi5);
                        const int n_ = n0 + wc * 64 + g6 * 8 + (l31 & 7);
                        const size_t idx = ((size_t)b * HDIM + ch) * NN + n_;
                        Vh[idx] = f2bf(acc[fi][fj][r]);   // V hi only
                    }
        }
    } else {
#pragma unroll
        for (int fi = 0; fi < 2; ++fi)
#pragma unroll
            for (int fj = 0; fj < 2; ++fj)
#pragma unroll
                for (int r = 0; r < 16; ++r) {
                    const int mrow = m0 + wr * 64 + fi * 32 + (r & 3) + 8 * (r >> 2) + 4 * hi5;
                    outF[((size_t)b * CIN + mrow) * NN + nn + fj * 32] =
                        acc[fi][fj][r] + bias[mrow];
                }
    }
}

// ---------------- MFMA flash attention v8 ----------------
// R6 structure (512 blocks, 4 waves x 32q, full 2048-key scan, LDS dbuf) with:
// m=0 fixed-base exp2 softmax (validated R7), P plain bf16, V plain bf16 (hi
// only) -> 16 MFMA/js (was 24), half the pack VALU, 48KB LDS.
__global__ __launch_bounds__(256, 2) void attn_mfma(
    const ushort_t* __restrict__ Qh, const ushort_t* __restrict__ Ql,
    const ushort_t* __restrict__ Kh, const ushort_t* __restrict__ Kl,
    const ushort_t* __restrict__ Vh,
    ushort_t* __restrict__ aoth, ushort_t* __restrict__ aotl) {
    // grid 512 = 8 xcd-slots x 4 bh x 16 qtiles (K/V of 4 heads ~ one L2)
    const int Lid = blockIdx.x;
    const int slot = Lid & 7, rest = Lid >> 3;
    const int bh = slot * 4 + (rest >> 4);
    const int qt = rest & 15;
    const int b = bh >> 4, h = bh & 15;
    const int wave = threadIdx.x >> 6;
    const int lane = threadIdx.x & 63;
    const int l31 = lane & 31;
    const int hi5 = lane >> 5;
    const int r7 = l31 & 7;
    const int q0 = qt * 128 + wave * 32;

    __shared__ __align__(16) ushort_t lsKh[2][4096], lsKl[2][4096], lsVh[2][4096];

    // Q fragments (one-time)
    bf16x8 qfh[4], qfl[4];
    {
        const ushort_t* qb  = Qh + ((size_t)bh * NN + q0 + l31) * DHEAD + hi5 * 8;
        const ushort_t* qlb = Ql + ((size_t)bh * NN + q0 + l31) * DHEAD + hi5 * 8;
#pragma unroll
        for (int c = 0; c < 4; ++c) {
            qfh[c] = *(const bf16x8*)(qb + c * 16);
            qfl[c] = *(const bf16x8*)(qlb + c * 16);
        }
    }

    // staging: wave0->Kh(8KB), wave1->Kl(8KB), wave2->Vh rows 0-31, wave3->Vh rows 32-63
    const size_t kbase = (size_t)bh * NN * DHEAD;
    const size_t vbase = (size_t)bh * DHEAD * NN;
    const ushort_t* gsel = (wave == 0) ? Kh + kbase
                         : (wave == 1) ? Kl + kbase
                                       : Vh + vbase;
    ushort_t* lsel = (wave == 0) ? lsKh[0]
                   : (wave == 1) ? lsKl[0]
                                 : lsVh[0];
    const bool isK = wave < 2;
    const int i0 = (wave == 3) ? 4 : 0;
    const int sr = lane >> 3, sg = lane & 7;

#define STAGE(BUF, J0)                                                         \
    {                                                                          \
        ushort_t* dst_ = lsel + (BUF) * 4096;                                  \
        if (isK) {                                                             \
            _Pragma("unroll") for (int i_ = 0; i_ < 8; ++i_)                   \
                GLDS(gsel + (size_t)((J0) + i_ * 8 + sr) * DHEAD + sg * 8,     \
                     dst_ + i_ * 512);                                         \
        } else {                                                               \
            _Pragma("unroll") for (int i_ = 0; i_ < 4; ++i_) {                 \
                const int ii_ = i0 + i_;                                       \
                GLDS(gsel + (size_t)(ii_ * 8 + sr) * NN + (J0) + sg * 8,       \
                     dst_ + ii_ * 512);                                        \
            }                                                                  \
        }                                                                      \
    }

    f32x16 o0, o1, zz;
#pragma unroll
    for (int r = 0; r < 16; ++r) { o0[r] = 0.f; o1[r] = 0.f; zz[r] = 0.f; }
    float l = 0.f;

    STAGE(0, 0);
    __syncthreads();

#pragma unroll 1
    for (int t = 0; t < NN / 64; ++t) {
        const int buf = t & 1;
        if (t < NN / 64 - 1) STAGE(buf ^ 1, (t + 1) * 64);

#pragma unroll
        for (int js = 0; js < 2; ++js) {
            // K fragments from LDS (swizzled)
            bf16x8 kh_[4], kl_[4];
            const int kro = (js * 32 + l31) * 64;
#pragma unroll
            for (int c = 0; c < 4; ++c) {
                const int go = ((2 * c + hi5) ^ r7) * 8;
                kh_[c] = *(const bf16x8*)(lsKh[buf] + kro + go);
                kl_[c] = *(const bf16x8*)(lsKl[buf] + kro + go);
            }
            __builtin_amdgcn_s_setprio(1);
            f32x16 sA = mfma32(kh_[0], qfh[0], zz);
            sA = mfma32(kl_[0], qfh[0], sA);
            sA = mfma32(kh_[0], qfl[0], sA);
            sA = mfma32(kh_[1], qfh[1], sA);
            sA = mfma32(kl_[1], qfh[1], sA);
            sA = mfma32(kh_[1], qfl[1], sA);
            f32x16 sB = mfma32(kh_[2], qfh[2], zz);
            sB = mfma32(kl_[2], qfh[2], sB);
            sB = mfma32(kh_[2], qfl[2], sB);
            sB = mfma32(kh_[3], qfh[3], sB);
            sB = mfma32(kl_[3], qfh[3], sB);
            sB = mfma32(kh_[3], qfl[3], sB);
            __builtin_amdgcn_s_setprio(0);

            // m=0 fixed-base softmax: p = exp2(s)
            f32x16 s;
            float ps = 0.f;
#pragma unroll
            for (int r = 0; r < 16; ++r) {
                s[r] = __builtin_amdgcn_exp2f(sA[r] + sB[r]);
                ps += s[r];
            }
            l += ps + __shfl_xor(ps, 32);

            // pack P (hi only) + blend-shuffle redistribution
            bf16x8 pB[2];
#pragma unroll
            for (int jc = 0; jc < 2; ++jc) {
                unsigned P0 = cvt_pk_bf16(s[8 * jc + 0], s[8 * jc + 1]);
                unsigned P1 = cvt_pk_bf16(s[8 * jc + 2], s[8 * jc + 3]);
                unsigned P2 = cvt_pk_bf16(s[8 * jc + 4], s[8 * jc + 5]);
                unsigned P3 = cvt_pk_bf16(s[8 * jc + 6], s[8 * jc + 7]);
                unsigned ta = hi5 ? P0 : P2, tb = hi5 ? P1 : P3;
                unsigned sa = __shfl_xor((int)ta, 32), sb = __shfl_xor((int)tb, 32);
                U4 th;
                th.u[0] = hi5 ? sa : P0; th.u[1] = hi5 ? sb : P1;
                th.u[2] = hi5 ? P2 : sa; th.u[3] = hi5 ? P3 : sb;
                pB[jc] = th.v;
            }

            // PV: 4 MFMA cluster (V hi only)
            bf16x8 v00, v01, v10, v11;
            {
                const int vro0 = (0 * 32 + l31) * 64;
                const int vro1 = (1 * 32 + l31) * 64;
                v00 = *(const bf16x8*)(lsVh[buf] + vro0 + (((js * 4 + 0 + hi5) ^ r7) * 8));
                v01 = *(const bf16x8*)(lsVh[buf] + vro1 + (((js * 4 + 0 + hi5) ^ r7) * 8));
                v10 = *(const bf16x8*)(lsVh[buf] + vro0 + (((js * 4 + 2 + hi5) ^ r7) * 8));
                v11 = *(const bf16x8*)(lsVh[buf] + vro1 + (((js * 4 + 2 + hi5) ^ r7) * 8));
            }
            __builtin_amdgcn_s_setprio(1);
            o0 = mfma32(v00, pB[0], o0);
            o1 = mfma32(v01, pB[0], o1);
            o0 = mfma32(v10, pB[1], o0);
            o1 = mfma32(v11, pB[1], o1);
            __builtin_amdgcn_s_setprio(0);
        }
        __syncthreads();
    }
#undef STAGE

    // epilogue: write transposed hi/lo bf16 aot[b][n][h*64+d]
    const float invl = 1.0f / l;
    const size_t rowb = ((size_t)b * NN + q0 + l31) * HDIM + h * DHEAD;
#pragma unroll
    for (int dt = 0; dt < 2; ++dt)
#pragma unroll
        for (int g = 0; g < 4; ++g) {
            ushort4v hv, lv;
#pragma unroll
            for (int i = 0; i < 4; ++i) {
                float f = (dt ? o1[4 * g + i] : o0[4 * g + i]) * invl;
                ushort_t h2 = f2bf(f);
                hv[i] = h2;
                lv[i] = f2bf(f - bf2f(h2));
            }
            size_t o = rowb + dt * 32 + 8 * g + 4 * hi5;
            *(ushort4v*)(aoth + o) = hv;
            *(ushort4v*)(aotl + o) = lv;
        }
}

// ---------------- launch ----------------
extern "C" void kernel_launch(void* const* d_in, const int* in_sizes, int n_in,
                              void* d_out, int out_size, void* d_ws, size_t ws_size,
                              hipStream_t stream) {
    const float* x     = (const float*)d_in[0];
    const float* w_qkv = (const float*)d_in[1];
    const float* w_out = (const float*)d_in[2];
    const float* b_out = (const float*)d_in[3];
    float* out = (float*)d_out;

    ushort_t* ws_u = (ushort_t*)d_ws;
    ushort_t* Qh = ws_u;
    ushort_t* Ql = Qh + QSZ;
    ushort_t* Kh = Ql + QSZ;
    ushort_t* Kl = Kh + QSZ;
    ushort_t* Vh = Kl + QSZ;
    // (old Vl slot dead — layout kept for simplicity)
    ushort_t* shared_u = ws_u + 6 * QSZ;
    ushort_t* wqh = shared_u;
    ushort_t* wql = wqh + (size_t)O3 * CIN;
    ushort_t* aoth = shared_u;
    ushort_t* aotl = aoth + (size_t)BATCH * NN * HDIM;
    ushort_t* woh = ws_u;
    ushort_t* wol = woh + (size_t)CIN * HDIM;
    ushort_t* xth = (ushort_t*)d_out;
    ushort_t* xtl = xth + (size_t)BATCH * NN * CIN;

    if (ws_size < (6 * QSZ + 2 * (size_t)BATCH * NN * CIN) * sizeof(ushort_t)) return;

    // 1) weight + input conversions
    convert_split<<<1536, 256, 0, stream>>>(w_qkv, wqh, wql, O3 * CIN / 8);
    transpose_cvt<<<dim3(NN / 32, CIN / 32, BATCH), 256, 0, stream>>>(x, xth, xtl);

    // 2) QKV projection -> Q (exp2-scaled) plain, K swizzled hi/lo, V hi only
    gemm_mfma<0><<<dim3(NN / 128, O3 / 128, BATCH), 256, 0, stream>>>(
        wqh, wql, xth, xtl, nullptr, nullptr, Qh, Ql, Kh, Kl, Vh);

    // 3) flash attention (single-pass, LDS-staged, 512 blocks) -> aot hi/lo
    attn_mfma<<<dim3(512), 256, 0, stream>>>(
        Qh, Ql, Kh, Kl, Vh, aoth, aotl);

    // 4) w_out conversion into dead Q region
    convert_split<<<512, 256, 0, stream>>>(w_out, woh, wol, CIN * HDIM / 8);

    // 5) output projection + bias -> out f32
    gemm_mfma<1><<<dim3(NN / 128, HDIM / 128, BATCH), 256, 0, stream>>>(
        woh, wol, aoth, aotl, b_out, out, nullptr, nullptr, nullptr, nullptr,
        nullptr);
}

// Round 10
// 172.804 us; speedup vs baseline: 1.7735x; 1.2717x over previous
//
#include <hip/hip_runtime.h>
#include <hip/hip_bf16.h>

// Problem constants
#define BATCH 2
#define CIN   1024
#define NN    2048
#define HEADS 16
#define DHEAD 64
#define HDIM  1024
#define O3    3072
#define QSCALE 0.125f
// 0.125 * log2(e): Q pre-scale so softmax runs in exp2 domain
#define QSCALE_L2E 0.18033688011112042f
#define QSZ ((size_t)BATCH * HEADS * NN * DHEAD)  // 4,194,304 elements

typedef unsigned short ushort_t;
typedef __attribute__((ext_vector_type(8))) short bf16x8;
typedef __attribute__((ext_vector_type(8))) unsigned short ushort8;
typedef __attribute__((ext_vector_type(4))) unsigned short ushort4v;
typedef __attribute__((ext_vector_type(16))) float f32x16;

__device__ inline ushort_t f2bf(float f) {
    unsigned u = __builtin_bit_cast(unsigned, f);
    unsigned r = u + 0x7fffu + ((u >> 16) & 1u);
    return (ushort_t)(r >> 16);
}
__device__ inline float bf2f(ushort_t h) {
    return __builtin_bit_cast(float, (unsigned)h << 16);
}
__device__ inline f32x16 mfma32(bf16x8 a, bf16x8 b, f32x16 c) {
    return __builtin_amdgcn_mfma_f32_32x32x16_bf16(a, b, c, 0, 0, 0);
}
// packed 2xbf16 (RNE): low half = bf16(a), high half = bf16(b)
__device__ inline unsigned cvt_pk_bf16(float a, float b) {
    unsigned r;
    asm("v_cvt_pk_bf16_f32 %0, %1, %2" : "=v"(r) : "v"(a), "v"(b));
    return r;
}

union U4 { unsigned u[4]; bf16x8 v; };

// global -> LDS direct (16B per lane); LDS dest is wave-uniform base + lane*16
#define GLDS(gp, lp) __builtin_amdgcn_global_load_lds( \
    (__attribute__((address_space(1))) void*)(gp),     \
    (__attribute__((address_space(3))) void*)(lp), 16, 0, 0)

// ---------------- elementwise f32 -> bf16 hi/lo split ----------------
__global__ __launch_bounds__(256) void convert_split(const float* __restrict__ in,
                                                     ushort_t* __restrict__ hi,
                                                     ushort_t* __restrict__ lo,
                                                     int n8) {
    int t = blockIdx.x * 256 + threadIdx.x;
    if (t >= n8) return;
    size_t base = (size_t)t * 8;
    float4 a = *(const float4*)(in + base);
    float4 b = *(const float4*)(in + base + 4);
    float v[8] = {a.x, a.y, a.z, a.w, b.x, b.y, b.z, b.w};
    ushort8 hv, lv;
#pragma unroll
    for (int i = 0; i < 8; ++i) {
        ushort_t h = f2bf(v[i]);
        hv[i] = h;
        lv[i] = f2bf(v[i] - bf2f(h));
    }
    *(ushort8*)(hi + base) = hv;
    *(ushort8*)(lo + base) = lv;
}

// ------------- transpose: in f32 [B][CIN][NN] -> out hi bf16 [B][NN][CIN] -------------
__global__ __launch_bounds__(256) void transpose_cvt(const float* __restrict__ in,
                                                     ushort_t* __restrict__ th) {
    __shared__ float T[32][33];
    const int b = blockIdx.z;
    const int n0 = blockIdx.x * 32, c0 = blockIdx.y * 32;
    const int t = threadIdx.x;
    const int r = t >> 3, q = t & 7;
    float4 v = *(const float4*)(in + ((size_t)b * CIN + c0 + r) * NN + n0 + q * 4);
    T[r][q * 4 + 0] = v.x; T[r][q * 4 + 1] = v.y;
    T[r][q * 4 + 2] = v.z; T[r][q * 4 + 3] = v.w;
    __syncthreads();
    ushort4v hv;
#pragma unroll
    for (int i = 0; i < 4; ++i) hv[i] = f2bf(T[q * 4 + i][r]);
    size_t o = ((size_t)b * NN + n0 + r) * CIN + c0 + q * 4;
    *(ushort4v*)(th + o) = hv;
}

// ---------------- MFMA GEMM ----------------
// MODE 0 (QKV): 2-term split (al*bh + ah*bh) — B (x^T) staged hi only.
//   Epilogue: Q [bh][n][64] bf16 scaled by 0.125*log2e; K same w/ granule^(row&7)
//   swizzle; V [b*1024+ch][n] w/ n-granule^(ch&7) swizzle. All hi-only.
// MODE 1 (out-proj): full 3-term split + bias -> f32 out.
template<int MODE>
__global__ __launch_bounds__(256, 3) void gemm_mfma(
    const ushort_t* __restrict__ Ah, const ushort_t* __restrict__ Al,
    const ushort_t* __restrict__ Bth, const ushort_t* __restrict__ Btl,
    const float* __restrict__ bias, float* __restrict__ outF,
    ushort_t* __restrict__ Qh, ushort_t* __restrict__ Kh,
    ushort_t* __restrict__ Vh) {

    __shared__ __align__(16) ushort_t lsAh[4096], lsAl[4096], lsBh[4096];
    __shared__ __align__(16) ushort_t lsBl[(MODE == 1) ? 4096 : 16];

    const int b  = blockIdx.z;
    const int n0 = blockIdx.x * 128;
    const int m0 = blockIdx.y * 128;
    const int tid = threadIdx.x;
    const int wave = tid >> 6, lane = tid & 63;
    const int l31 = lane & 31, hi5 = lane >> 5;
    const int wr = wave >> 1, wc = wave & 1;

    const int srow = lane >> 2;
    const int kswz = 8 * ((lane & 3) ^ ((lane >> 3) & 3));
    const ushort_t* gAh = Ah  + (size_t)(m0 + wave * 16 + srow) * CIN + kswz;
    const ushort_t* gAl = Al  + (size_t)(m0 + wave * 16 + srow) * CIN + kswz;
    const ushort_t* gBh = Bth + ((size_t)b * NN + n0 + wave * 16 + srow) * CIN + kswz;
    const ushort_t* gBl = (MODE == 1)
        ? Btl + ((size_t)b * NN + n0 + wave * 16 + srow) * CIN + kswz : nullptr;
    ushort_t* dAh = lsAh + wave * 512;
    ushort_t* dAl = lsAl + wave * 512;
    ushort_t* dBh = lsBh + wave * 512;
    ushort_t* dBl = lsBl + ((MODE == 1) ? wave * 512 : 0);

    const int rswz = ((l31 >> 1) & 3) * 8;
    int offA[2][2], offB[2][2];
#pragma unroll
    for (int f = 0; f < 2; ++f)
#pragma unroll
        for (int kh = 0; kh < 2; ++kh) {
            offA[f][kh] = (wr * 64 + f * 32 + l31) * 64 + ((kh * 16 + hi5 * 8) ^ rswz) * 2;
            offB[f][kh] = (wc * 64 + f * 32 + l31) * 64 + ((kh * 16 + hi5 * 8) ^ rswz) * 2;
        }

    f32x16 acc[2][2];
#pragma unroll
    for (int i = 0; i < 2; ++i)
#pragma unroll
        for (int j = 0; j < 2; ++j)
#pragma unroll
            for (int r = 0; r < 16; ++r) acc[i][j][r] = 0.f;

    for (int k0 = 0; k0 < CIN; k0 += 32) {
        __syncthreads();
        GLDS(gAh + k0,            dAh);
        GLDS(gAh + 64 * CIN + k0, dAh + 2048);
        GLDS(gAl + k0,            dAl);
        GLDS(gAl + 64 * CIN + k0, dAl + 2048);
        GLDS(gBh + k0,            dBh);
        GLDS(gBh + 64 * CIN + k0, dBh + 2048);
        if constexpr (MODE == 1) {
            GLDS(gBl + k0,            dBl);
            GLDS(gBl + 64 * CIN + k0, dBl + 2048);
        }
        __syncthreads();
#pragma unroll
        for (int kh = 0; kh < 2; ++kh) {
            bf16x8 a_h[2], a_l[2], b_h[2], b_l[2];
#pragma unroll
            for (int f = 0; f < 2; ++f) {
                a_h[f] = *(const bf16x8*)((const char*)lsAh + offA[f][kh]);
                a_l[f] = *(const bf16x8*)((const char*)lsAl + offA[f][kh]);
                b_h[f] = *(const bf16x8*)((const char*)lsBh + offB[f][kh]);
                if constexpr (MODE == 1)
                    b_l[f] = *(const bf16x8*)((const char*)lsBl + offB[f][kh]);
            }
#pragma unroll
            for (int fi = 0; fi < 2; ++fi)
#pragma unroll
                for (int fj = 0; fj < 2; ++fj) {
                    acc[fi][fj] = mfma32(a_l[fi], b_h[fj], acc[fi][fj]);
                    if constexpr (MODE == 1)
                        acc[fi][fj] = mfma32(a_h[fi], b_l[fj], acc[fi][fj]);
                    acc[fi][fj] = mfma32(a_h[fi], b_h[fj], acc[fi][fj]);
                }
        }
    }

    const int nn = n0 + wc * 64 + l31;

    if constexpr (MODE == 0) {
        const int region = m0 >> 10;  // 0=Q 1=K 2=V (uniform per block)
        if (region < 2) {
            const float scale = (region == 0) ? QSCALE_L2E : 1.0f;
            ushort_t* H = (region == 0) ? Qh : Kh;
            const int head = ((m0 & 1023) >> 6) + wr;
            const size_t bh_base = (size_t)(b * HEADS + head) * NN;
#pragma unroll
            for (int fj = 0; fj < 2; ++fj) {
                const size_t rowb = (bh_base + nn + fj * 32) * DHEAD;
#pragma unroll
                for (int fi = 0; fi < 2; ++fi) {
#pragma unroll
                    for (int g = 0; g < 4; ++g) {
                        ushort4v hv;
#pragma unroll
                        for (int i = 0; i < 4; ++i)
                            hv[i] = f2bf(acc[fi][fj][4 * g + i] * scale);
                        // K gets granule swizzle ^(row&7); row&7 == l31&7
                        const int e = (region == 1)
                            ? (((fi * 4 + g) ^ (l31 & 7)) * 8 + 4 * hi5)
                            : (fi * 32 + 4 * hi5 + 8 * g);
                        *(ushort4v*)(H + rowb + e) = hv;
                    }
                }
            }
        } else {
            const int ch0 = (m0 - 2048) + wr * 64;
#pragma unroll
            for (int fi = 0; fi < 2; ++fi)
#pragma unroll
                for (int fj = 0; fj < 2; ++fj)
#pragma unroll
                    for (int r = 0; r < 16; ++r) {
                        const int ch = ch0 + fi * 32 + (r & 3) + 8 * (r >> 2) + 4 * hi5;
                        const int g6 = (fj * 4 + (l31 >> 3)) ^ ((r & 3) + 4 * hi5);
                        const int n_ = n0 + wc * 64 + g6 * 8 + (l31 & 7);
                        const size_t idx = ((size_t)b * HDIM + ch) * NN + n_;
                        Vh[idx] = f2bf(acc[fi][fj][r]);
                    }
        }
    } else {
#pragma unroll
        for (int fi = 0; fi < 2; ++fi)
#pragma unroll
            for (int fj = 0; fj < 2; ++fj)
#pragma unroll
                for (int r = 0; r < 16; ++r) {
                    const int mrow = m0 + wr * 64 + fi * 32 + (r & 3) + 8 * (r >> 2) + 4 * hi5;
                    outF[((size_t)b * CIN + mrow) * NN + nn + fj * 32] =
                        acc[fi][fj][r] + bias[mrow];
                }
    }
}

// ---------------- MFMA flash attention v9 ----------------
// R8 structure (512 blocks, 4 waves x 32q, 2048-key scan, LDS dbuf) with plain
// bf16 QK^T: 4 MFMA QK + 4 MFMA PV per 32-key step, 32KB LDS, hi-only Q/K/V.
__global__ __launch_bounds__(256, 2) void attn_mfma(
    const ushort_t* __restrict__ Qh, const ushort_t* __restrict__ Kh,
    const ushort_t* __restrict__ Vh,
    ushort_t* __restrict__ aoth, ushort_t* __restrict__ aotl) {
    // grid 512 = 8 xcd-slots x 4 bh x 16 qtiles (K/V of 4 heads ~ one L2)
    const int Lid = blockIdx.x;
    const int slot = Lid & 7, rest = Lid >> 3;
    const int bh = slot * 4 + (rest >> 4);
    const int qt = rest & 15;
    const int b = bh >> 4, h = bh & 15;
    const int wave = threadIdx.x >> 6;
    const int lane = threadIdx.x & 63;
    const int l31 = lane & 31;
    const int hi5 = lane >> 5;
    const int r7 = l31 & 7;
    const int q0 = qt * 128 + wave * 32;

    __shared__ __align__(16) ushort_t lsKh[2][4096], lsVh[2][4096];

    // Q fragments (one-time, hi only)
    bf16x8 qfh[4];
    {
        const ushort_t* qb = Qh + ((size_t)bh * NN + q0 + l31) * DHEAD + hi5 * 8;
#pragma unroll
        for (int c = 0; c < 4; ++c) qfh[c] = *(const bf16x8*)(qb + c * 16);
    }

    // staging: waves 0,1 split Kh; waves 2,3 split Vh; 4 GLDS each
    const size_t kbase = (size_t)bh * NN * DHEAD;
    const size_t vbase = (size_t)bh * DHEAD * NN;
    const bool isK = wave < 2;
    const ushort_t* gsel = isK ? Kh + kbase : Vh + vbase;
    ushort_t* lsel = isK ? lsKh[0] : lsVh[0];
    const int i0 = (wave & 1) * 4;
    const int sr = lane >> 3, sg = lane & 7;

#define STAGE(BUF, J0)                                                         \
    {                                                                          \
        ushort_t* dst_ = lsel + (BUF) * 4096;                                  \
        _Pragma("unroll") for (int i_ = 0; i_ < 4; ++i_) {                     \
            const int ii_ = i0 + i_;                                           \
            const ushort_t* s_ = isK                                           \
                ? gsel + (size_t)((J0) + ii_ * 8 + sr) * DHEAD + sg * 8        \
                : gsel + (size_t)(ii_ * 8 + sr) * NN + (J0) + sg * 8;          \
            GLDS(s_, dst_ + ii_ * 512);                                        \
        }                                                                      \
    }

    f32x16 o0, o1, zz;
#pragma unroll
    for (int r = 0; r < 16; ++r) { o0[r] = 0.f; o1[r] = 0.f; zz[r] = 0.f; }
    float l = 0.f;

    STAGE(0, 0);
    __syncthreads();

#pragma unroll 1
    for (int t = 0; t < NN / 64; ++t) {
        const int buf = t & 1;
        if (t < NN / 64 - 1) STAGE(buf ^ 1, (t + 1) * 64);

#pragma unroll
        for (int js = 0; js < 2; ++js) {
            // K fragments from LDS (swizzled)
            bf16x8 kh_[4];
            const int kro = (js * 32 + l31) * 64;
#pragma unroll
            for (int c = 0; c < 4; ++c) {
                const int go = ((2 * c + hi5) ^ r7) * 8;
                kh_[c] = *(const bf16x8*)(lsKh[buf] + kro + go);
            }
            __builtin_amdgcn_s_setprio(1);
            f32x16 sA = mfma32(kh_[0], qfh[0], zz);
            sA = mfma32(kh_[1], qfh[1], sA);
            f32x16 sB = mfma32(kh_[2], qfh[2], zz);
            sB = mfma32(kh_[3], qfh[3], sB);
            __builtin_amdgcn_s_setprio(0);

            // m=0 fixed-base softmax: p = exp2(s)
            f32x16 s;
            float ps = 0.f;
#pragma unroll
            for (int r = 0; r < 16; ++r) {
                s[r] = __builtin_amdgcn_exp2f(sA[r] + sB[r]);
                ps += s[r];
            }
            l += ps + __shfl_xor(ps, 32);

            // pack P (bf16) + blend-shuffle redistribution
            bf16x8 pB[2];
#pragma unroll
            for (int jc = 0; jc < 2; ++jc) {
                unsigned P0 = cvt_pk_bf16(s[8 * jc + 0], s[8 * jc + 1]);
                unsigned P1 = cvt_pk_bf16(s[8 * jc + 2], s[8 * jc + 3]);
                unsigned P2 = cvt_pk_bf16(s[8 * jc + 4], s[8 * jc + 5]);
                unsigned P3 = cvt_pk_bf16(s[8 * jc + 6], s[8 * jc + 7]);
                unsigned ta = hi5 ? P0 : P2, tb = hi5 ? P1 : P3;
                unsigned sa = __shfl_xor((int)ta, 32), sb = __shfl_xor((int)tb, 32);
                U4 th;
                th.u[0] = hi5 ? sa : P0; th.u[1] = hi5 ? sb : P1;
                th.u[2] = hi5 ? P2 : sa; th.u[3] = hi5 ? P3 : sb;
                pB[jc] = th.v;
            }

            // PV: 4 MFMA cluster
            bf16x8 v00, v01, v10, v11;
            {
                const int vro0 = (0 * 32 + l31) * 64;
                const int vro1 = (1 * 32 + l31) * 64;
                v00 = *(const bf16x8*)(lsVh[buf] + vro0 + (((js * 4 + 0 + hi5) ^ r7) * 8));
                v01 = *(const bf16x8*)(lsVh[buf] + vro1 + (((js * 4 + 0 + hi5) ^ r7) * 8));
                v10 = *(const bf16x8*)(lsVh[buf] + vro0 + (((js * 4 + 2 + hi5) ^ r7) * 8));
                v11 = *(const bf16x8*)(lsVh[buf] + vro1 + (((js * 4 + 2 + hi5) ^ r7) * 8));
            }
            __builtin_amdgcn_s_setprio(1);
            o0 = mfma32(v00, pB[0], o0);
            o1 = mfma32(v01, pB[0], o1);
            o0 = mfma32(v10, pB[1], o0);
            o1 = mfma32(v11, pB[1], o1);
            __builtin_amdgcn_s_setprio(0);
        }
        __syncthreads();
    }
#undef STAGE

    // epilogue: write transposed hi/lo bf16 aot[b][n][h*64+d]
    const float invl = 1.0f / l;
    const size_t rowb = ((size_t)b * NN + q0 + l31) * HDIM + h * DHEAD;
#pragma unroll
    for (int dt = 0; dt < 2; ++dt)
#pragma unroll
        for (int g = 0; g < 4; ++g) {
            ushort4v hv, lv;
#pragma unroll
            for (int i = 0; i < 4; ++i) {
                float f = (dt ? o1[4 * g + i] : o0[4 * g + i]) * invl;
                ushort_t h2 = f2bf(f);
                hv[i] = h2;
                lv[i] = f2bf(f - bf2f(h2));
            }
            size_t o = rowb + dt * 32 + 8 * g + 4 * hi5;
            *(ushort4v*)(aoth + o) = hv;
            *(ushort4v*)(aotl + o) = lv;
        }
}

// ---------------- launch ----------------
extern "C" void kernel_launch(void* const* d_in, const int* in_sizes, int n_in,
                              void* d_out, int out_size, void* d_ws, size_t ws_size,
                              hipStream_t stream) {
    const float* x     = (const float*)d_in[0];
    const float* w_qkv = (const float*)d_in[1];
    const float* w_out = (const float*)d_in[2];
    const float* b_out = (const float*)d_in[3];
    float* out = (float*)d_out;

    ushort_t* ws_u = (ushort_t*)d_ws;
    ushort_t* Qh = ws_u;                       // hi-only now
    ushort_t* Kh = Qh + QSZ;
    ushort_t* Vh = Kh + QSZ;
    ushort_t* shared_u = ws_u + 6 * QSZ;       // wq hi/lo, then aot hi/lo
    ushort_t* wqh = shared_u;
    ushort_t* wql = wqh + (size_t)O3 * CIN;
    ushort_t* aoth = shared_u;
    ushort_t* aotl = aoth + (size_t)BATCH * NN * HDIM;
    ushort_t* woh = ws_u + 3 * QSZ;            // w_out hi/lo into dead region
    ushort_t* wol = woh + (size_t)CIN * HDIM;
    ushort_t* xth = (ushort_t*)d_out;          // x^T hi in d_out (dead later)

    if (ws_size < (6 * QSZ + 2 * (size_t)BATCH * NN * CIN) * sizeof(ushort_t)) return;

    // 1) weight + input conversions
    convert_split<<<1536, 256, 0, stream>>>(w_qkv, wqh, wql, O3 * CIN / 8);
    transpose_cvt<<<dim3(NN / 32, CIN / 32, BATCH), 256, 0, stream>>>(x, xth);

    // 2) QKV projection (2-term split) -> Q/K/V bf16 (Q exp2-scaled; K/V swizzled)
    gemm_mfma<0><<<dim3(NN / 128, O3 / 128, BATCH), 256, 0, stream>>>(
        wqh, wql, xth, nullptr, nullptr, nullptr, Qh, Kh, Vh);

    // 3) flash attention (bf16 QK^T, 512 blocks) -> aot hi/lo
    attn_mfma<<<dim3(512), 256, 0, stream>>>(Qh, Kh, Vh, aoth, aotl);

    // 4) w_out conversion into dead region
    convert_split<<<512, 256, 0, stream>>>(w_out, woh, wol, CIN * HDIM / 8);

    // 5) output projection (3-term split) + bias -> out f32
    gemm_mfma<1><<<dim3(NN / 128, HDIM / 128, BATCH), 256, 0, stream>>>(
        woh, wol, aoth, aotl, b_out, out, nullptr, nullptr, nullptr);
}

// Round 11
// 145.335 us; speedup vs baseline: 2.1087x; 1.1890x over previous
//
#include <hip/hip_runtime.h>
#include <hip/hip_bf16.h>

// Problem constants
#define BATCH 2
#define CIN   1024
#define NN    2048
#define HEADS 16
#define DHEAD 64
#define HDIM  1024
#define O3    3072
#define QSCALE 0.125f
// 0.125 * log2(e): Q pre-scale so softmax runs in exp2 domain
#define QSCALE_L2E 0.18033688011112042f
#define QSZ ((size_t)BATCH * HEADS * NN * DHEAD)  // 4,194,304 elements

typedef unsigned short ushort_t;
typedef __attribute__((ext_vector_type(8))) short bf16x8;
typedef __attribute__((ext_vector_type(8))) unsigned short ushort8;
typedef __attribute__((ext_vector_type(4))) unsigned short ushort4v;
typedef __attribute__((ext_vector_type(16))) float f32x16;

__device__ inline ushort_t f2bf(float f) {
    unsigned u = __builtin_bit_cast(unsigned, f);
    unsigned r = u + 0x7fffu + ((u >> 16) & 1u);
    return (ushort_t)(r >> 16);
}
__device__ inline float bf2f(ushort_t h) {
    return __builtin_bit_cast(float, (unsigned)h << 16);
}
__device__ inline f32x16 mfma32(bf16x8 a, bf16x8 b, f32x16 c) {
    return __builtin_amdgcn_mfma_f32_32x32x16_bf16(a, b, c, 0, 0, 0);
}
// packed 2xbf16 (RNE): low half = bf16(a), high half = bf16(b)
__device__ inline unsigned cvt_pk_bf16(float a, float b) {
    unsigned r;
    asm("v_cvt_pk_bf16_f32 %0, %1, %2" : "=v"(r) : "v"(a), "v"(b));
    return r;
}

union U4 { unsigned u[4]; bf16x8 v; };

// global -> LDS direct (16B per lane); LDS dest is wave-uniform base + lane*16
#define GLDS(gp, lp) __builtin_amdgcn_global_load_lds( \
    (__attribute__((address_space(1))) void*)(gp),     \
    (__attribute__((address_space(3))) void*)(lp), 16, 0, 0)

// ---------------- elementwise f32 -> bf16 (hi only) ----------------
__global__ __launch_bounds__(256) void convert_bf16(const float* __restrict__ in,
                                                    ushort_t* __restrict__ hi,
                                                    int n8) {
    int t = blockIdx.x * 256 + threadIdx.x;
    if (t >= n8) return;
    size_t base = (size_t)t * 8;
    float4 a = *(const float4*)(in + base);
    float4 b = *(const float4*)(in + base + 4);
    float v[8] = {a.x, a.y, a.z, a.w, b.x, b.y, b.z, b.w};
    ushort8 hv;
#pragma unroll
    for (int i = 0; i < 8; ++i) hv[i] = f2bf(v[i]);
    *(ushort8*)(hi + base) = hv;
}

// ---------------- elementwise f32 -> bf16 hi/lo split ----------------
__global__ __launch_bounds__(256) void convert_split(const float* __restrict__ in,
                                                     ushort_t* __restrict__ hi,
                                                     ushort_t* __restrict__ lo,
                                                     int n8) {
    int t = blockIdx.x * 256 + threadIdx.x;
    if (t >= n8) return;
    size_t base = (size_t)t * 8;
    float4 a = *(const float4*)(in + base);
    float4 b = *(const float4*)(in + base + 4);
    float v[8] = {a.x, a.y, a.z, a.w, b.x, b.y, b.z, b.w};
    ushort8 hv, lv;
#pragma unroll
    for (int i = 0; i < 8; ++i) {
        ushort_t h = f2bf(v[i]);
        hv[i] = h;
        lv[i] = f2bf(v[i] - bf2f(h));
    }
    *(ushort8*)(hi + base) = hv;
    *(ushort8*)(lo + base) = lv;
}

// ------------- transpose: in f32 [B][CIN][NN] -> out hi bf16 [B][NN][CIN] -------------
__global__ __launch_bounds__(256) void transpose_cvt(const float* __restrict__ in,
                                                     ushort_t* __restrict__ th) {
    __shared__ float T[32][33];
    const int b = blockIdx.z;
    const int n0 = blockIdx.x * 32, c0 = blockIdx.y * 32;
    const int t = threadIdx.x;
    const int r = t >> 3, q = t & 7;
    float4 v = *(const float4*)(in + ((size_t)b * CIN + c0 + r) * NN + n0 + q * 4);
    T[r][q * 4 + 0] = v.x; T[r][q * 4 + 1] = v.y;
    T[r][q * 4 + 2] = v.z; T[r][q * 4 + 3] = v.w;
    __syncthreads();
    ushort4v hv;
#pragma unroll
    for (int i = 0; i < 4; ++i) hv[i] = f2bf(T[q * 4 + i][r]);
    size_t o = ((size_t)b * NN + n0 + r) * CIN + c0 + q * 4;
    *(ushort4v*)(th + o) = hv;
}

// ---------------- MFMA GEMM ----------------
// MODE 0 (QKV): plain bf16 1-term (score errors average out in softmax/PV).
//   Epilogue: Q [bh][n][64] bf16 scaled by 0.125*log2e; K same w/ granule^(row&7)
//   swizzle; V [b*1024+ch][n] w/ n-granule^(ch&7) swizzle. All hi-only.
// MODE 1 (out-proj): full 3-term split + bias -> f32 out (direct output path).
template<int MODE>
__global__ __launch_bounds__(256, 3) void gemm_mfma(
    const ushort_t* __restrict__ Ah, const ushort_t* __restrict__ Al,
    const ushort_t* __restrict__ Bth, const ushort_t* __restrict__ Btl,
    const float* __restrict__ bias, float* __restrict__ outF,
    ushort_t* __restrict__ Qh, ushort_t* __restrict__ Kh,
    ushort_t* __restrict__ Vh) {

    __shared__ __align__(16) ushort_t lsAh[4096], lsBh[4096];
    __shared__ __align__(16) ushort_t lsAl[(MODE == 1) ? 4096 : 16];
    __shared__ __align__(16) ushort_t lsBl[(MODE == 1) ? 4096 : 16];

    const int b  = blockIdx.z;
    const int n0 = blockIdx.x * 128;
    const int m0 = blockIdx.y * 128;
    const int tid = threadIdx.x;
    const int wave = tid >> 6, lane = tid & 63;
    const int l31 = lane & 31, hi5 = lane >> 5;
    const int wr = wave >> 1, wc = wave & 1;

    const int srow = lane >> 2;
    const int kswz = 8 * ((lane & 3) ^ ((lane >> 3) & 3));
    const ushort_t* gAh = Ah  + (size_t)(m0 + wave * 16 + srow) * CIN + kswz;
    const ushort_t* gBh = Bth + ((size_t)b * NN + n0 + wave * 16 + srow) * CIN + kswz;
    const ushort_t* gAl = (MODE == 1)
        ? Al  + (size_t)(m0 + wave * 16 + srow) * CIN + kswz : nullptr;
    const ushort_t* gBl = (MODE == 1)
        ? Btl + ((size_t)b * NN + n0 + wave * 16 + srow) * CIN + kswz : nullptr;
    ushort_t* dAh = lsAh + wave * 512;
    ushort_t* dBh = lsBh + wave * 512;
    ushort_t* dAl = lsAl + ((MODE == 1) ? wave * 512 : 0);
    ushort_t* dBl = lsBl + ((MODE == 1) ? wave * 512 : 0);

    const int rswz = ((l31 >> 1) & 3) * 8;
    int offA[2][2], offB[2][2];
#pragma unroll
    for (int f = 0; f < 2; ++f)
#pragma unroll
        for (int kh = 0; kh < 2; ++kh) {
            offA[f][kh] = (wr * 64 + f * 32 + l31) * 64 + ((kh * 16 + hi5 * 8) ^ rswz) * 2;
            offB[f][kh] = (wc * 64 + f * 32 + l31) * 64 + ((kh * 16 + hi5 * 8) ^ rswz) * 2;
        }

    f32x16 acc[2][2];
#pragma unroll
    for (int i = 0; i < 2; ++i)
#pragma unroll
        for (int j = 0; j < 2; ++j)
#pragma unroll
            for (int r = 0; r < 16; ++r) acc[i][j][r] = 0.f;

    for (int k0 = 0; k0 < CIN; k0 += 32) {
        __syncthreads();
        GLDS(gAh + k0,            dAh);
        GLDS(gAh + 64 * CIN + k0, dAh + 2048);
        GLDS(gBh + k0,            dBh);
        GLDS(gBh + 64 * CIN + k0, dBh + 2048);
        if constexpr (MODE == 1) {
            GLDS(gAl + k0,            dAl);
            GLDS(gAl + 64 * CIN + k0, dAl + 2048);
            GLDS(gBl + k0,            dBl);
            GLDS(gBl + 64 * CIN + k0, dBl + 2048);
        }
        __syncthreads();
#pragma unroll
        for (int kh = 0; kh < 2; ++kh) {
            bf16x8 a_h[2], a_l[2], b_h[2], b_l[2];
#pragma unroll
            for (int f = 0; f < 2; ++f) {
                a_h[f] = *(const bf16x8*)((const char*)lsAh + offA[f][kh]);
                b_h[f] = *(const bf16x8*)((const char*)lsBh + offB[f][kh]);
                if constexpr (MODE == 1) {
                    a_l[f] = *(const bf16x8*)((const char*)lsAl + offA[f][kh]);
                    b_l[f] = *(const bf16x8*)((const char*)lsBl + offB[f][kh]);
                }
            }
#pragma unroll
            for (int fi = 0; fi < 2; ++fi)
#pragma unroll
                for (int fj = 0; fj < 2; ++fj) {
                    if constexpr (MODE == 1) {
                        acc[fi][fj] = mfma32(a_l[fi], b_h[fj], acc[fi][fj]);
                        acc[fi][fj] = mfma32(a_h[fi], b_l[fj], acc[fi][fj]);
                    }
                    acc[fi][fj] = mfma32(a_h[fi], b_h[fj], acc[fi][fj]);
                }
        }
    }

    const int nn = n0 + wc * 64 + l31;

    if constexpr (MODE == 0) {
        const int region = m0 >> 10;  // 0=Q 1=K 2=V (uniform per block)
        if (region < 2) {
            const float scale = (region == 0) ? QSCALE_L2E : 1.0f;
            ushort_t* H = (region == 0) ? Qh : Kh;
            const int head = ((m0 & 1023) >> 6) + wr;
            const size_t bh_base = (size_t)(b * HEADS + head) * NN;
#pragma unroll
            for (int fj = 0; fj < 2; ++fj) {
                const size_t rowb = (bh_base + nn + fj * 32) * DHEAD;
#pragma unroll
                for (int fi = 0; fi < 2; ++fi) {
#pragma unroll
                    for (int g = 0; g < 4; ++g) {
                        ushort4v hv;
#pragma unroll
                        for (int i = 0; i < 4; ++i)
                            hv[i] = f2bf(acc[fi][fj][4 * g + i] * scale);
                        // K gets granule swizzle ^(row&7); row&7 == l31&7
                        const int e = (region == 1)
                            ? (((fi * 4 + g) ^ (l31 & 7)) * 8 + 4 * hi5)
                            : (fi * 32 + 4 * hi5 + 8 * g);
                        *(ushort4v*)(H + rowb + e) = hv;
                    }
                }
            }
        } else {
            const int ch0 = (m0 - 2048) + wr * 64;
#pragma unroll
            for (int fi = 0; fi < 2; ++fi)
#pragma unroll
                for (int fj = 0; fj < 2; ++fj)
#pragma unroll
                    for (int r = 0; r < 16; ++r) {
                        const int ch = ch0 + fi * 32 + (r & 3) + 8 * (r >> 2) + 4 * hi5;
                        const int g6 = (fj * 4 + (l31 >> 3)) ^ ((r & 3) + 4 * hi5);
                        const int n_ = n0 + wc * 64 + g6 * 8 + (l31 & 7);
                        const size_t idx = ((size_t)b * HDIM + ch) * NN + n_;
                        Vh[idx] = f2bf(acc[fi][fj][r]);
                    }
        }
    } else {
#pragma unroll
        for (int fi = 0; fi < 2; ++fi)
#pragma unroll
            for (int fj = 0; fj < 2; ++fj)
#pragma unroll
                for (int r = 0; r < 16; ++r) {
                    const int mrow = m0 + wr * 64 + fi * 32 + (r & 3) + 8 * (r >> 2) + 4 * hi5;
                    outF[((size_t)b * CIN + mrow) * NN + nn + fj * 32] =
                        acc[fi][fj][r] + bias[mrow];
                }
    }
}

// ---------------- MFMA flash attention v10 ----------------
// 512 blocks, 4 waves x 32q, 2048-key scan; 128-key LDS tiles (dbuf, 64KB),
// bf16 QK/PV, m=0 exp2 softmax, per-lane l (one epilogue shuffle), tree-sum ps.
__global__ __launch_bounds__(256, 2) void attn_mfma(
    const ushort_t* __restrict__ Qh, const ushort_t* __restrict__ Kh,
    const ushort_t* __restrict__ Vh,
    ushort_t* __restrict__ aoth, ushort_t* __restrict__ aotl) {
    // grid 512 = 8 xcd-slots x 4 bh x 16 qtiles (K/V of 4 heads ~ one L2)
    const int Lid = blockIdx.x;
    const int slot = Lid & 7, rest = Lid >> 3;
    const int bh = slot * 4 + (rest >> 4);
    const int qt = rest & 15;
    const int b = bh >> 4, h = bh & 15;
    const int wave = threadIdx.x >> 6;
    const int lane = threadIdx.x & 63;
    const int l31 = lane & 31;
    const int hi5 = lane >> 5;
    const int r7 = l31 & 7;
    const int q0 = qt * 128 + wave * 32;

    __shared__ __align__(16) ushort_t lsK[2][8192], lsV[2][8192];

    // Q fragments (one-time)
    bf16x8 qfh[4];
    {
        const ushort_t* qb = Qh + ((size_t)bh * NN + q0 + l31) * DHEAD + hi5 * 8;
#pragma unroll
        for (int c = 0; c < 4; ++c) qfh[c] = *(const bf16x8*)(qb + c * 16);
    }

    // staging: waves 0,1 split K (128 rows x 64d); waves 2,3 split V (64d x 128n)
    const size_t kbase = (size_t)bh * NN * DHEAD;
    const size_t vbase = (size_t)bh * DHEAD * NN;
    const bool isK = wave < 2;
    const ushort_t* gsel = isK ? Kh + kbase : Vh + vbase;
    ushort_t* lsel = isK ? lsK[0] : lsV[0];
    const int c0 = (wave & 1) * 8;              // 8 chunks of 512 elems each
    const int srK = lane >> 3, sgK = lane & 7;  // K chunk: 8 rows x 64 d
    const int srV = lane >> 4, sgV = lane & 15; // V chunk: 4 rows x 128 n

#define STAGE(BUF, J0)                                                         \
    {                                                                          \
        ushort_t* dst_ = lsel + (BUF) * 8192;                                  \
        _Pragma("unroll") for (int i_ = 0; i_ < 8; ++i_) {                     \
            const int ii_ = c0 + i_;                                           \
            const ushort_t* s_ = isK                                           \
                ? gsel + (size_t)((J0) + ii_ * 8 + srK) * DHEAD + sgK * 8      \
                : gsel + (size_t)(ii_ * 4 + srV) * NN + (J0) + sgV * 8;        \
            GLDS(s_, dst_ + ii_ * 512);                                        \
        }                                                                      \
    }

    f32x16 o0, o1, zz;
#pragma unroll
    for (int r = 0; r < 16; ++r) { o0[r] = 0.f; o1[r] = 0.f; zz[r] = 0.f; }
    float l = 0.f;

    STAGE(0, 0);
    __syncthreads();

#pragma unroll 1
    for (int t = 0; t < NN / 128; ++t) {
        const int buf = t & 1;
        if (t < NN / 128 - 1) STAGE(buf ^ 1, (t + 1) * 128);

#pragma unroll
        for (int js = 0; js < 4; ++js) {
            // K fragments from LDS (swizzled)
            bf16x8 kh_[4];
            const int kro = (js * 32 + l31) * 64;
#pragma unroll
            for (int c = 0; c < 4; ++c) {
                const int go = ((2 * c + hi5) ^ r7) * 8;
                kh_[c] = *(const bf16x8*)(lsK[buf] + kro + go);
            }
            __builtin_amdgcn_s_setprio(1);
            f32x16 sA = mfma32(kh_[0], qfh[0], zz);
            sA = mfma32(kh_[1], qfh[1], sA);
            f32x16 sB = mfma32(kh_[2], qfh[2], zz);
            sB = mfma32(kh_[3], qfh[3], sB);
            __builtin_amdgcn_s_setprio(0);

            // m=0 fixed-base softmax: p = exp2(s); tree-sum; per-lane l
            f32x16 s;
#pragma unroll
            for (int r = 0; r < 16; ++r)
                s[r] = __builtin_amdgcn_exp2f(sA[r] + sB[r]);
            float t0 = (s[0] + s[1]) + (s[2] + s[3]);
            float t1 = (s[4] + s[5]) + (s[6] + s[7]);
            float t2 = (s[8] + s[9]) + (s[10] + s[11]);
            float t3 = (s[12] + s[13]) + (s[14] + s[15]);
            l += (t0 + t1) + (t2 + t3);

            // pack P (bf16) + blend-shuffle redistribution
            bf16x8 pB[2];
#pragma unroll
            for (int jc = 0; jc < 2; ++jc) {
                unsigned P0 = cvt_pk_bf16(s[8 * jc + 0], s[8 * jc + 1]);
                unsigned P1 = cvt_pk_bf16(s[8 * jc + 2], s[8 * jc + 3]);
                unsigned P2 = cvt_pk_bf16(s[8 * jc + 4], s[8 * jc + 5]);
                unsigned P3 = cvt_pk_bf16(s[8 * jc + 6], s[8 * jc + 7]);
                unsigned ta = hi5 ? P0 : P2, tb = hi5 ? P1 : P3;
                unsigned sa = __shfl_xor((int)ta, 32), sb = __shfl_xor((int)tb, 32);
                U4 th;
                th.u[0] = hi5 ? sa : P0; th.u[1] = hi5 ? sb : P1;
                th.u[2] = hi5 ? P2 : sa; th.u[3] = hi5 ? P3 : sb;
                pB[jc] = th.v;
            }

            // PV: V tile is [64 d][128 n]; key block js -> 64-group (js>>1)
            const int g64 = (js >> 1) * 64;
            const int js2 = js & 1;
            bf16x8 v00, v01, v10, v11;
            {
                const int vro0 = (0 * 32 + l31) * 128 + g64;
                const int vro1 = (1 * 32 + l31) * 128 + g64;
                v00 = *(const bf16x8*)(lsV[buf] + vro0 + (((js2 * 4 + 0 + hi5) ^ r7) * 8));
                v01 = *(const bf16x8*)(lsV[buf] + vro1 + (((js2 * 4 + 0 + hi5) ^ r7) * 8));
                v10 = *(const bf16x8*)(lsV[buf] + vro0 + (((js2 * 4 + 2 + hi5) ^ r7) * 8));
                v11 = *(const bf16x8*)(lsV[buf] + vro1 + (((js2 * 4 + 2 + hi5) ^ r7) * 8));
            }
            __builtin_amdgcn_s_setprio(1);
            o0 = mfma32(v00, pB[0], o0);
            o1 = mfma32(v01, pB[0], o1);
            o0 = mfma32(v10, pB[1], o0);
            o1 = mfma32(v11, pB[1], o1);
            __builtin_amdgcn_s_setprio(0);
        }
        __syncthreads();
    }
#undef STAGE

    // epilogue: one l-combine shuffle, write transposed hi/lo bf16 aot
    const float ltot = l + __shfl_xor(l, 32);
    const float invl = 1.0f / ltot;
    const size_t rowb = ((size_t)b * NN + q0 + l31) * HDIM + h * DHEAD;
#pragma unroll
    for (int dt = 0; dt < 2; ++dt)
#pragma unroll
        for (int g = 0; g < 4; ++g) {
            ushort4v hv, lv;
#pragma unroll
            for (int i = 0; i < 4; ++i) {
                float f = (dt ? o1[4 * g + i] : o0[4 * g + i]) * invl;
                ushort_t h2 = f2bf(f);
                hv[i] = h2;
                lv[i] = f2bf(f - bf2f(h2));
            }
            size_t o = rowb + dt * 32 + 8 * g + 4 * hi5;
            *(ushort4v*)(aoth + o) = hv;
            *(ushort4v*)(aotl + o) = lv;
        }
}

// ---------------- launch ----------------
extern "C" void kernel_launch(void* const* d_in, const int* in_sizes, int n_in,
                              void* d_out, int out_size, void* d_ws, size_t ws_size,
                              hipStream_t stream) {
    const float* x     = (const float*)d_in[0];
    const float* w_qkv = (const float*)d_in[1];
    const float* w_out = (const float*)d_in[2];
    const float* b_out = (const float*)d_in[3];
    float* out = (float*)d_out;

    ushort_t* ws_u = (ushort_t*)d_ws;
    ushort_t* Qh = ws_u;
    ushort_t* Kh = Qh + QSZ;
    ushort_t* Vh = Kh + QSZ;
    ushort_t* woh = ws_u + 3 * QSZ;            // w_out hi/lo (free region)
    ushort_t* wol = woh + (size_t)CIN * HDIM;
    ushort_t* shared_u = ws_u + 6 * QSZ;       // wq hi (phase A), aot hi/lo (phase B)
    ushort_t* wqh = shared_u;
    ushort_t* aoth = shared_u;
    ushort_t* aotl = aoth + (size_t)BATCH * NN * HDIM;
    ushort_t* xth = (ushort_t*)d_out;          // x^T bf16 in d_out (dead later)

    if (ws_size < (6 * QSZ + 2 * (size_t)BATCH * NN * CIN) * sizeof(ushort_t)) return;

    // 1) conversions: w_qkv hi-only, x^T hi-only, w_out hi/lo
    convert_bf16<<<1536, 256, 0, stream>>>(w_qkv, wqh, O3 * CIN / 8);
    transpose_cvt<<<dim3(NN / 32, CIN / 32, BATCH), 256, 0, stream>>>(x, xth);
    convert_split<<<512, 256, 0, stream>>>(w_out, woh, wol, CIN * HDIM / 8);

    // 2) QKV projection (plain bf16) -> Q (exp2-scaled) / K / V (swizzled)
    gemm_mfma<0><<<dim3(NN / 128, O3 / 128, BATCH), 256, 0, stream>>>(
        wqh, nullptr, xth, nullptr, nullptr, nullptr, Qh, Kh, Vh);

    // 3) flash attention (128-key tiles, 512 blocks) -> aot hi/lo
    attn_mfma<<<dim3(512), 256, 0, stream>>>(Qh, Kh, Vh, aoth, aotl);

    // 4) output projection (3-term split) + bias -> out f32
    gemm_mfma<1><<<dim3(NN / 128, HDIM / 128, BATCH), 256, 0, stream>>>(
        woh, wol, aoth, aotl, b_out, out, nullptr, nullptr, nullptr);
}